// Round 1
// baseline (904.685 us; speedup 1.0000x reference)
//
#include <hip/hip_runtime.h>
#include <hip/hip_bf16.h>

#define N_NODES 100000
#define N_EDGES 1600000
#define N_GRAPHS 1024

// ---------------- degree histogram ----------------
__global__ void count_deg_kernel(const int* __restrict__ dst, int* __restrict__ cnt, int E) {
    int i = blockIdx.x * blockDim.x + threadIdx.x;
    int stride = gridDim.x * blockDim.x;
    for (; i < E; i += stride) atomicAdd(&cnt[dst[i]], 1);
}

// ---------------- single-block exclusive scan over cnt -> rowptr ----------------
__global__ __launch_bounds__(1024) void scan_kernel(const int* __restrict__ cnt,
                                                    int* __restrict__ rowptr, int n) {
    __shared__ int partial[1024];
    int tid = threadIdx.x;
    int seg = (n + 1023) / 1024;
    int start = tid * seg;
    int end = min(start + seg, n);
    int s = 0;
    for (int i = start; i < end; ++i) s += cnt[i];
    partial[tid] = s;
    __syncthreads();
    for (int off = 1; off < 1024; off <<= 1) {
        int v = (tid >= off) ? partial[tid - off] : 0;
        __syncthreads();
        partial[tid] += v;
        __syncthreads();
    }
    int run = (tid > 0) ? partial[tid - 1] : 0;
    for (int i = start; i < end; ++i) { rowptr[i] = run; run += cnt[i]; }
    if (tid == 1023) rowptr[n] = partial[1023];
}

// ---------------- dinv = rsqrt(deg) with self-loop (+1) ----------------
__global__ void dinv_kernel(const int* __restrict__ cnt, float* __restrict__ dinv, int n) {
    int i = blockIdx.x * blockDim.x + threadIdx.x;
    if (i < n) dinv[i] = rsqrtf((float)cnt[i] + 1.0f);
}

// ---------------- CSR fill (group edge sources by dst) ----------------
__global__ void fill_csr_kernel(const int* __restrict__ src, const int* __restrict__ dst,
                                const int* __restrict__ rowptr, int* __restrict__ cursor,
                                int* __restrict__ esrc, int E) {
    int i = blockIdx.x * blockDim.x + threadIdx.x;
    int stride = gridDim.x * blockDim.x;
    for (; i < E; i += stride) {
        int d = dst[i];
        int pos = rowptr[d] + atomicAdd(&cursor[d], 1);
        esrc[pos] = src[i];
    }
}

// ---------------- ts = dinv[row] * (X @ W)  (row-major W [F_IN][F_OUT]) ----------------
template <int F_IN, int F_OUT>
__global__ __launch_bounds__(256) void gemm_scale_kernel(const float* __restrict__ X,
                                                         const float* __restrict__ W,
                                                         const float* __restrict__ dinv,
                                                         float* __restrict__ TS, int n) {
    constexpr int ROWS = 8;
    constexpr int RSTRIDE = 256 / F_OUT;   // 4 (F_OUT=64) or 2 (F_OUT=128)
    constexpr int ACCN = ROWS / RSTRIDE;   // 2 or 4
    __shared__ float xs[ROWS][F_IN + 1];
    int row0 = blockIdx.x * ROWS;          // n % ROWS == 0 for N=100000
    for (int idx = threadIdx.x; idx < ROWS * F_IN; idx += 256) {
        int r = idx / F_IN, k = idx % F_IN;
        xs[r][k] = X[(size_t)(row0 + r) * F_IN + k];
    }
    __syncthreads();
    int col = threadIdx.x % F_OUT;
    int rs = threadIdx.x / F_OUT;
    float acc[ACCN];
#pragma unroll
    for (int a = 0; a < ACCN; ++a) acc[a] = 0.0f;
    for (int k = 0; k < F_IN; ++k) {
        float w = W[k * F_OUT + col];
#pragma unroll
        for (int a = 0; a < ACCN; ++a) acc[a] += xs[rs + a * RSTRIDE][k] * w;
    }
#pragma unroll
    for (int a = 0; a < ACCN; ++a) {
        int r = row0 + rs + a * RSTRIDE;
        TS[(size_t)r * F_OUT + col] = dinv[r] * acc[a];
    }
}

// ---------------- out = relu(dinv[i]*(sum_{e->i} ts[src] + ts[i]) + b) ----------------
template <int F>
__global__ __launch_bounds__(256) void pull_agg_kernel(const float* __restrict__ TS,
                                                       const int* __restrict__ rowptr,
                                                       const int* __restrict__ esrc,
                                                       const float* __restrict__ dinv,
                                                       const float* __restrict__ bias,
                                                       float* __restrict__ OUT, int n) {
    constexpr int TPN = F / 4;         // threads per node (float4 per thread)
    constexpr int NPB = 256 / TPN;     // nodes per block
    int li = threadIdx.x / TPN;
    int t = threadIdx.x % TPN;
    int node = blockIdx.x * NPB + li;
    if (node >= n) return;
    const float4* TS4 = (const float4*)TS;
    float4 acc = TS4[(size_t)node * TPN + t];   // self-loop term
    int jend = rowptr[node + 1];
    for (int j = rowptr[node]; j < jend; ++j) {
        int s = esrc[j];
        float4 v = TS4[(size_t)s * TPN + t];
        acc.x += v.x; acc.y += v.y; acc.z += v.z; acc.w += v.w;
    }
    float dv = dinv[node];
    float4 bb = ((const float4*)bias)[t];
    float4 o;
    o.x = fmaxf(dv * acc.x + bb.x, 0.0f);
    o.y = fmaxf(dv * acc.y + bb.y, 0.0f);
    o.z = fmaxf(dv * acc.z + bb.z, 0.0f);
    o.w = fmaxf(dv * acc.w + bb.w, 0.0f);
    ((float4*)OUT)[(size_t)node * TPN + t] = o;
}

// ---------------- mean-pool (batch sorted -> binary search range) + FC ----------------
__global__ __launch_bounds__(128) void pool_fc_kernel(const float* __restrict__ H,
                                                      const int* __restrict__ batch,
                                                      const float* __restrict__ Wfc,
                                                      const float* __restrict__ bfc,
                                                      float* __restrict__ OUT, int n) {
    int g = blockIdx.x;
    __shared__ int se[2];
    __shared__ float pooled[128];
    if (threadIdx.x < 2) {
        int target = g + threadIdx.x;  // lower_bound(batch, target)
        int lo = 0, hi = n;
        while (lo < hi) {
            int mid = (lo + hi) >> 1;
            if (batch[mid] < target) lo = mid + 1; else hi = mid;
        }
        se[threadIdx.x] = lo;
    }
    __syncthreads();
    int start = se[0], end = se[1];
    float s = 0.0f;
    for (int i = start; i < end; ++i) s += H[(size_t)i * 128 + threadIdx.x];
    float cntf = (float)max(end - start, 1);
    pooled[threadIdx.x] = s / cntf;
    __syncthreads();
    if (threadIdx.x < 10) {
        float o = bfc[threadIdx.x];
        for (int k = 0; k < 128; ++k) o += pooled[k] * Wfc[k * 10 + threadIdx.x];
        OUT[g * 10 + threadIdx.x] = o;
    }
}

extern "C" void kernel_launch(void* const* d_in, const int* in_sizes, int n_in,
                              void* d_out, int out_size, void* d_ws, size_t ws_size,
                              hipStream_t stream) {
    const int N = N_NODES, E = N_EDGES, G = N_GRAPHS;
    const float* x = (const float*)d_in[0];
    const int* ei = (const int*)d_in[1];
    const int* batch = (const int*)d_in[2];
    const float* W1 = (const float*)d_in[3];
    const float* b1 = (const float*)d_in[4];
    const float* W2 = (const float*)d_in[5];
    const float* b2 = (const float*)d_in[6];
    const float* W3 = (const float*)d_in[7];
    const float* b3 = (const float*)d_in[8];
    const float* Wfc = (const float*)d_in[9];
    const float* bfc = (const float*)d_in[10];
    const int* src = ei;
    const int* dst = ei + E;

    char* ws = (char*)d_ws;
    size_t off = 0;
    auto alloc = [&](size_t bytes) {
        void* p = ws + off;
        off = (off + bytes + 255) & ~(size_t)255;
        return p;
    };
    float* dinv = (float*)alloc((size_t)N * 4);
    int* cnt = (int*)alloc((size_t)N * 4);          // degree histogram, reused as fill cursor
    int* rowptr = (int*)alloc((size_t)(N + 1) * 4);
    int* esrc = (int*)alloc((size_t)E * 4);
    float* T = (float*)alloc((size_t)N * 128 * 4);  // ts buffer
    float* A = (float*)alloc((size_t)N * 128 * 4);  // layer outputs (ping)
    float* B = (float*)alloc((size_t)N * 128 * 4);  // layer outputs (pong)

    // ---- graph preprocessing ----
    hipMemsetAsync(cnt, 0, (size_t)N * 4, stream);
    count_deg_kernel<<<2048, 256, 0, stream>>>(dst, cnt, E);
    scan_kernel<<<1, 1024, 0, stream>>>(cnt, rowptr, N);
    dinv_kernel<<<(N + 255) / 256, 256, 0, stream>>>(cnt, dinv, N);
    hipMemsetAsync(cnt, 0, (size_t)N * 4, stream);
    fill_csr_kernel<<<2048, 256, 0, stream>>>(src, dst, rowptr, cnt, esrc, E);

    // ---- layer 1: 128 -> 64 ----
    gemm_scale_kernel<128, 64><<<N / 8, 256, 0, stream>>>(x, W1, dinv, T, N);
    pull_agg_kernel<64><<<N / 16, 256, 0, stream>>>(T, rowptr, esrc, dinv, b1, A, N);
    // ---- layer 2: 64 -> 128 ----
    gemm_scale_kernel<64, 128><<<N / 8, 256, 0, stream>>>(A, W2, dinv, T, N);
    pull_agg_kernel<128><<<N / 8, 256, 0, stream>>>(T, rowptr, esrc, dinv, b2, B, N);
    // ---- layer 3: 128 -> 128 ----
    gemm_scale_kernel<128, 128><<<N / 8, 256, 0, stream>>>(B, W3, dinv, T, N);
    pull_agg_kernel<128><<<N / 8, 256, 0, stream>>>(T, rowptr, esrc, dinv, b3, A, N);
    // ---- mean pool + FC ----
    pool_fc_kernel<<<G, 128, 0, stream>>>(A, batch, Wfc, bfc, (float*)d_out, N);
}

// Round 2
// 765.088 us; speedup vs baseline: 1.1825x; 1.1825x over previous
//
#include <hip/hip_runtime.h>
#include <hip/hip_bf16.h>

#define N_NODES 100000
#define N_EDGES 1600000
#define N_GRAPHS 1024
#define SCAN_CHUNK 1024   // elements per scan block (256 threads x int4)

// ---------------- degree histogram ----------------
__global__ void count_deg_kernel(const int* __restrict__ dst, int* __restrict__ cnt, int E) {
    int i = blockIdx.x * blockDim.x + threadIdx.x;
    int stride = gridDim.x * blockDim.x;
    for (; i < E; i += stride) atomicAdd(&cnt[dst[i]], 1);
}

// ---------------- hierarchical scan, pass 1: per-chunk sums ----------------
__global__ __launch_bounds__(256) void scan_sums_kernel(const int* __restrict__ cnt,
                                                        int* __restrict__ bsums, int n) {
    __shared__ int red[256];
    int tid = threadIdx.x;
    int i0 = blockIdx.x * SCAN_CHUNK + tid * 4;
    int s = 0;
#pragma unroll
    for (int k = 0; k < 4; ++k) {
        int i = i0 + k;
        if (i < n) s += cnt[i];
    }
    red[tid] = s;
    __syncthreads();
    for (int off = 128; off > 0; off >>= 1) {
        if (tid < off) red[tid] += red[tid + off];
        __syncthreads();
    }
    if (tid == 0) bsums[blockIdx.x] = red[0];
}

// ---------------- pass 2: per-chunk exclusive scan + global offset ----------------
// writes rowptr[0..n] and a second copy (cursor) used directly by fill_csr
__global__ __launch_bounds__(256) void scan_write_kernel(const int* __restrict__ cnt,
                                                         const int* __restrict__ bsums,
                                                         int* __restrict__ rowptr,
                                                         int* __restrict__ cursor,
                                                         int n, int nb) {
    __shared__ int pre[256];
    __shared__ int lds[256];
    int tid = threadIdx.x;
    int b = blockIdx.x;
    // prefix of bsums[0..b) (nb <= 256)
    pre[tid] = (tid < b && tid < nb) ? bsums[tid] : 0;
    __syncthreads();
    for (int off = 128; off > 0; off >>= 1) {
        if (tid < off) pre[tid] += pre[tid + off];
        __syncthreads();
    }
    int blockOffset = pre[0];
    int i0 = b * SCAN_CHUNK + tid * 4;
    int e[4];
#pragma unroll
    for (int k = 0; k < 4; ++k) e[k] = (i0 + k < n) ? cnt[i0 + k] : 0;
    int ts = e[0] + e[1] + e[2] + e[3];
    lds[tid] = ts;
    __syncthreads();
    // inclusive Hillis-Steele over thread sums
    for (int off = 1; off < 256; off <<= 1) {
        int v = (tid >= off) ? lds[tid - off] : 0;
        __syncthreads();
        lds[tid] += v;
        __syncthreads();
    }
    int run = blockOffset + lds[tid] - ts;  // exclusive
#pragma unroll
    for (int k = 0; k < 4; ++k) {
        int i = i0 + k;
        if (i < n) { rowptr[i] = run; cursor[i] = run; }
        run += e[k];
    }
    if (b == nb - 1 && tid == 255) rowptr[n] = run;  // grand total
}

// ---------------- dinv = rsqrt(deg) with self-loop (+1) ----------------
__global__ void dinv_kernel(const int* __restrict__ cnt, float* __restrict__ dinv, int n) {
    int i = blockIdx.x * blockDim.x + threadIdx.x;
    if (i < n) dinv[i] = rsqrtf((float)cnt[i] + 1.0f);
}

// ---------------- CSR fill (group edge sources by dst) ----------------
__global__ void fill_csr_kernel(const int* __restrict__ src, const int* __restrict__ dst,
                                int* __restrict__ cursor, int* __restrict__ esrc, int E) {
    int i = blockIdx.x * blockDim.x + threadIdx.x;
    int stride = gridDim.x * blockDim.x;
    for (; i < E; i += stride) {
        int pos = atomicAdd(&cursor[dst[i]], 1);
        esrc[pos] = src[i];
    }
}

// ---------------- ts = dinv[row] * (X @ W)  (row-major W [F_IN][F_OUT]) ----------------
template <int F_IN, int F_OUT>
__global__ __launch_bounds__(256) void gemm_scale_kernel(const float* __restrict__ X,
                                                         const float* __restrict__ W,
                                                         const float* __restrict__ dinv,
                                                         float* __restrict__ TS, int n) {
    constexpr int ROWS = 8;
    constexpr int RSTRIDE = 256 / F_OUT;   // 4 (F_OUT=64) or 2 (F_OUT=128)
    constexpr int ACCN = ROWS / RSTRIDE;   // 2 or 4
    __shared__ float xs[ROWS][F_IN + 1];
    int row0 = blockIdx.x * ROWS;          // n % ROWS == 0 for N=100000
    for (int idx = threadIdx.x; idx < ROWS * F_IN; idx += 256) {
        int r = idx / F_IN, k = idx % F_IN;
        xs[r][k] = X[(size_t)(row0 + r) * F_IN + k];
    }
    __syncthreads();
    int col = threadIdx.x % F_OUT;
    int rs = threadIdx.x / F_OUT;
    float acc[ACCN];
#pragma unroll
    for (int a = 0; a < ACCN; ++a) acc[a] = 0.0f;
    for (int k = 0; k < F_IN; ++k) {
        float w = W[k * F_OUT + col];
#pragma unroll
        for (int a = 0; a < ACCN; ++a) acc[a] += xs[rs + a * RSTRIDE][k] * w;
    }
#pragma unroll
    for (int a = 0; a < ACCN; ++a) {
        int r = row0 + rs + a * RSTRIDE;
        TS[(size_t)r * F_OUT + col] = dinv[r] * acc[a];
    }
}

// ---------------- out = relu(dinv[i]*(sum_{e->i} ts[src] + ts[i]) + b) ----------------
template <int F>
__global__ __launch_bounds__(256) void pull_agg_kernel(const float* __restrict__ TS,
                                                       const int* __restrict__ rowptr,
                                                       const int* __restrict__ esrc,
                                                       const float* __restrict__ dinv,
                                                       const float* __restrict__ bias,
                                                       float* __restrict__ OUT, int n) {
    constexpr int TPN = F / 4;         // threads per node (float4 per thread)
    constexpr int NPB = 256 / TPN;     // nodes per block
    int li = threadIdx.x / TPN;
    int t = threadIdx.x % TPN;
    int node = blockIdx.x * NPB + li;
    if (node >= n) return;
    const float4* TS4 = (const float4*)TS;
    float4 acc = TS4[(size_t)node * TPN + t];   // self-loop term
    int jend = rowptr[node + 1];
    for (int j = rowptr[node]; j < jend; ++j) {
        int s = esrc[j];
        float4 v = TS4[(size_t)s * TPN + t];
        acc.x += v.x; acc.y += v.y; acc.z += v.z; acc.w += v.w;
    }
    float dv = dinv[node];
    float4 bb = ((const float4*)bias)[t];
    float4 o;
    o.x = fmaxf(dv * acc.x + bb.x, 0.0f);
    o.y = fmaxf(dv * acc.y + bb.y, 0.0f);
    o.z = fmaxf(dv * acc.z + bb.z, 0.0f);
    o.w = fmaxf(dv * acc.w + bb.w, 0.0f);
    ((float4*)OUT)[(size_t)node * TPN + t] = o;
}

// ---------------- mean-pool (batch sorted -> binary search range) + FC ----------------
__global__ __launch_bounds__(128) void pool_fc_kernel(const float* __restrict__ H,
                                                      const int* __restrict__ batch,
                                                      const float* __restrict__ Wfc,
                                                      const float* __restrict__ bfc,
                                                      float* __restrict__ OUT, int n) {
    int g = blockIdx.x;
    __shared__ int se[2];
    __shared__ float pooled[128];
    if (threadIdx.x < 2) {
        int target = g + threadIdx.x;  // lower_bound(batch, target)
        int lo = 0, hi = n;
        while (lo < hi) {
            int mid = (lo + hi) >> 1;
            if (batch[mid] < target) lo = mid + 1; else hi = mid;
        }
        se[threadIdx.x] = lo;
    }
    __syncthreads();
    int start = se[0], end = se[1];
    float s = 0.0f;
    for (int i = start; i < end; ++i) s += H[(size_t)i * 128 + threadIdx.x];
    float cntf = (float)max(end - start, 1);
    pooled[threadIdx.x] = s / cntf;
    __syncthreads();
    if (threadIdx.x < 10) {
        float o = bfc[threadIdx.x];
        for (int k = 0; k < 128; ++k) o += pooled[k] * Wfc[k * 10 + threadIdx.x];
        OUT[g * 10 + threadIdx.x] = o;
    }
}

extern "C" void kernel_launch(void* const* d_in, const int* in_sizes, int n_in,
                              void* d_out, int out_size, void* d_ws, size_t ws_size,
                              hipStream_t stream) {
    const int N = N_NODES, E = N_EDGES, G = N_GRAPHS;
    const float* x = (const float*)d_in[0];
    const int* ei = (const int*)d_in[1];
    const int* batch = (const int*)d_in[2];
    const float* W1 = (const float*)d_in[3];
    const float* b1 = (const float*)d_in[4];
    const float* W2 = (const float*)d_in[5];
    const float* b2 = (const float*)d_in[6];
    const float* W3 = (const float*)d_in[7];
    const float* b3 = (const float*)d_in[8];
    const float* Wfc = (const float*)d_in[9];
    const float* bfc = (const float*)d_in[10];
    const int* src = ei;
    const int* dst = ei + E;

    char* ws = (char*)d_ws;
    size_t off = 0;
    auto alloc = [&](size_t bytes) {
        void* p = ws + off;
        off = (off + bytes + 255) & ~(size_t)255;
        return p;
    };
    const int NB = (N + SCAN_CHUNK - 1) / SCAN_CHUNK;   // 98 (<=256 required)
    float* dinv = (float*)alloc((size_t)N * 4);
    int* cnt = (int*)alloc((size_t)N * 4);
    int* rowptr = (int*)alloc((size_t)(N + 1) * 4);
    int* cursor = (int*)alloc((size_t)N * 4);
    int* bsums = (int*)alloc((size_t)NB * 4);
    int* esrc = (int*)alloc((size_t)E * 4);
    float* T = (float*)alloc((size_t)N * 128 * 4);  // ts buffer
    float* A = (float*)alloc((size_t)N * 128 * 4);  // layer outputs (ping)
    float* B = (float*)alloc((size_t)N * 128 * 4);  // layer outputs (pong)

    // ---- graph preprocessing ----
    hipMemsetAsync(cnt, 0, (size_t)N * 4, stream);
    count_deg_kernel<<<2048, 256, 0, stream>>>(dst, cnt, E);
    scan_sums_kernel<<<NB, 256, 0, stream>>>(cnt, bsums, N);
    scan_write_kernel<<<NB, 256, 0, stream>>>(cnt, bsums, rowptr, cursor, N, NB);
    dinv_kernel<<<(N + 255) / 256, 256, 0, stream>>>(cnt, dinv, N);
    fill_csr_kernel<<<2048, 256, 0, stream>>>(src, dst, cursor, esrc, E);

    // ---- layer 1: 128 -> 64 ----
    gemm_scale_kernel<128, 64><<<N / 8, 256, 0, stream>>>(x, W1, dinv, T, N);
    pull_agg_kernel<64><<<N / 16, 256, 0, stream>>>(T, rowptr, esrc, dinv, b1, A, N);
    // ---- layer 2: 64 -> 128 ----
    gemm_scale_kernel<64, 128><<<N / 8, 256, 0, stream>>>(A, W2, dinv, T, N);
    pull_agg_kernel<128><<<N / 8, 256, 0, stream>>>(T, rowptr, esrc, dinv, b2, B, N);
    // ---- layer 3: 128 -> 128 ----
    gemm_scale_kernel<128, 128><<<N / 8, 256, 0, stream>>>(B, W3, dinv, T, N);
    pull_agg_kernel<128><<<N / 8, 256, 0, stream>>>(T, rowptr, esrc, dinv, b3, A, N);
    // ---- mean pool + FC ----
    pool_fc_kernel<<<G, 128, 0, stream>>>(A, batch, Wfc, bfc, (float*)d_out, N);
}

// Round 3
// 635.217 us; speedup vs baseline: 1.4242x; 1.2045x over previous
//
#include <hip/hip_runtime.h>
#include <hip/hip_bf16.h>

#define N_NODES 100000
#define N_EDGES 1600000
#define N_GRAPHS 1024
#define SCAN_CHUNK 1024     // elements per scan block (256 threads x int4)
#define BUK_SHIFT 7         // 128 nodes per bucket
#define NBUK 782            // ceil(100000 / 128)
#define SCAT_EPT 16         // edges per thread in bucket_scatter
#define SCAT_TILE (256 * SCAT_EPT)

// ---------------- bucket histogram (LDS-privatized) ----------------
__global__ __launch_bounds__(256) void bhist_kernel(const int* __restrict__ dst,
                                                    int* __restrict__ bhist, int E) {
    __shared__ int lh[NBUK];
    for (int i = threadIdx.x; i < NBUK; i += 256) lh[i] = 0;
    __syncthreads();
    int i = blockIdx.x * blockDim.x + threadIdx.x;
    int stride = gridDim.x * blockDim.x;
    for (; i < E; i += stride) atomicAdd(&lh[dst[i] >> BUK_SHIFT], 1);
    __syncthreads();
    for (int b = threadIdx.x; b < NBUK; b += 256)
        if (lh[b]) atomicAdd(&bhist[b], lh[b]);
}

// ---------------- exclusive scan of bucket hist (1 block) ----------------
__global__ __launch_bounds__(256) void bscan_kernel(const int* __restrict__ bhist,
                                                    int* __restrict__ boff,
                                                    int* __restrict__ bcursor) {
    __shared__ int lds[256];
    int tid = threadIdx.x;
    int i0 = tid * 4;
    int e[4];
#pragma unroll
    for (int k = 0; k < 4; ++k) e[k] = (i0 + k < NBUK) ? bhist[i0 + k] : 0;
    int ts = e[0] + e[1] + e[2] + e[3];
    lds[tid] = ts;
    __syncthreads();
    for (int off = 1; off < 256; off <<= 1) {
        int v = (tid >= off) ? lds[tid - off] : 0;
        __syncthreads();
        lds[tid] += v;
        __syncthreads();
    }
    int run = lds[tid] - ts;  // exclusive
#pragma unroll
    for (int k = 0; k < 4; ++k) {
        if (i0 + k < NBUK) { boff[i0 + k] = run; bcursor[i0 + k] = run; }
        run += e[k];
    }
    if (tid == 255) boff[NBUK] = lds[255];
}

// ---------------- scatter edges into bucket-sorted order ----------------
__global__ __launch_bounds__(256) void bucket_scatter_kernel(const int* __restrict__ src,
                                                             const int* __restrict__ dst,
                                                             int* __restrict__ bcursor,
                                                             int2* __restrict__ sorted, int E) {
    __shared__ int lhist[NBUK];
    __shared__ int lbase[NBUK];
    for (int i = threadIdx.x; i < NBUK; i += 256) lhist[i] = 0;
    __syncthreads();
    int base_i = blockIdx.x * SCAT_TILE;
    int s[SCAT_EPT], d[SCAT_EPT], lp[SCAT_EPT];
#pragma unroll
    for (int k = 0; k < SCAT_EPT; ++k) {
        int i = base_i + k * 256 + threadIdx.x;
        if (i < E) {
            s[k] = src[i];
            d[k] = dst[i];
            lp[k] = atomicAdd(&lhist[d[k] >> BUK_SHIFT], 1);
        }
    }
    __syncthreads();
    for (int b = threadIdx.x; b < NBUK; b += 256) {
        int c = lhist[b];
        lbase[b] = c ? atomicAdd(&bcursor[b], c) : 0;
    }
    __syncthreads();
#pragma unroll
    for (int k = 0; k < SCAT_EPT; ++k) {
        int i = base_i + k * 256 + threadIdx.x;
        if (i < E) {
            int b = d[k] >> BUK_SHIFT;
            sorted[lbase[b] + lp[k]] = make_int2(s[k], d[k]);
        }
    }
}

// ---------------- per-bucket node degree (dense writes) + dinv ----------------
__global__ __launch_bounds__(256) void bucket_count_kernel(const int2* __restrict__ sorted,
                                                           const int* __restrict__ boff,
                                                           int* __restrict__ cnt,
                                                           float* __restrict__ dinv, int n) {
    __shared__ int ncnt[128];
    int b = blockIdx.x;
    if (threadIdx.x < 128) ncnt[threadIdx.x] = 0;
    __syncthreads();
    int start = boff[b], end = boff[b + 1];
    for (int j = start + threadIdx.x; j < end; j += 256)
        atomicAdd(&ncnt[sorted[j].y & 127], 1);
    __syncthreads();
    if (threadIdx.x < 128) {
        int node = (b << BUK_SHIFT) + threadIdx.x;
        if (node < n) {
            int c = ncnt[threadIdx.x];
            cnt[node] = c;
            dinv[node] = rsqrtf((float)c + 1.0f);
        }
    }
}

// ---------------- hierarchical scan over cnt, pass 1: per-chunk sums ----------------
__global__ __launch_bounds__(256) void scan_sums_kernel(const int* __restrict__ cnt,
                                                        int* __restrict__ bsums, int n) {
    __shared__ int red[256];
    int tid = threadIdx.x;
    int i0 = blockIdx.x * SCAN_CHUNK + tid * 4;
    int s = 0;
#pragma unroll
    for (int k = 0; k < 4; ++k) {
        int i = i0 + k;
        if (i < n) s += cnt[i];
    }
    red[tid] = s;
    __syncthreads();
    for (int off = 128; off > 0; off >>= 1) {
        if (tid < off) red[tid] += red[tid + off];
        __syncthreads();
    }
    if (tid == 0) bsums[blockIdx.x] = red[0];
}

// ---------------- scan pass 2: rowptr ----------------
__global__ __launch_bounds__(256) void scan_write_kernel(const int* __restrict__ cnt,
                                                         const int* __restrict__ bsums,
                                                         int* __restrict__ rowptr,
                                                         int n, int nb) {
    __shared__ int pre[256];
    __shared__ int lds[256];
    int tid = threadIdx.x;
    int b = blockIdx.x;
    pre[tid] = (tid < b && tid < nb) ? bsums[tid] : 0;
    __syncthreads();
    for (int off = 128; off > 0; off >>= 1) {
        if (tid < off) pre[tid] += pre[tid + off];
        __syncthreads();
    }
    int blockOffset = pre[0];
    int i0 = b * SCAN_CHUNK + tid * 4;
    int e[4];
#pragma unroll
    for (int k = 0; k < 4; ++k) e[k] = (i0 + k < n) ? cnt[i0 + k] : 0;
    int ts = e[0] + e[1] + e[2] + e[3];
    lds[tid] = ts;
    __syncthreads();
    for (int off = 1; off < 256; off <<= 1) {
        int v = (tid >= off) ? lds[tid - off] : 0;
        __syncthreads();
        lds[tid] += v;
        __syncthreads();
    }
    int run = blockOffset + lds[tid] - ts;  // exclusive
#pragma unroll
    for (int k = 0; k < 4; ++k) {
        int i = i0 + k;
        if (i < n) rowptr[i] = run;
        run += e[k];
    }
    if (b == nb - 1 && tid == 255) rowptr[n] = run;
}

// ---------------- per-bucket CSR fill (dense writes via LDS cursors) ----------------
__global__ __launch_bounds__(256) void bucket_fill_kernel(const int2* __restrict__ sorted,
                                                          const int* __restrict__ boff,
                                                          const int* __restrict__ rowptr,
                                                          int* __restrict__ esrc, int n) {
    __shared__ int lbase[128];
    __shared__ int lcur[128];
    int b = blockIdx.x;
    if (threadIdx.x < 128) {
        int node = (b << BUK_SHIFT) + threadIdx.x;
        lbase[threadIdx.x] = (node < n) ? rowptr[node] : 0;
        lcur[threadIdx.x] = 0;
    }
    __syncthreads();
    int start = boff[b], end = boff[b + 1];
    for (int j = start + threadIdx.x; j < end; j += 256) {
        int2 e = sorted[j];
        int ln = e.y & 127;
        int off = atomicAdd(&lcur[ln], 1);
        esrc[lbase[ln] + off] = e.x;
    }
}

// ---------------- ts = dinv[row] * (X @ W)  (row-major W [F_IN][F_OUT]) ----------------
template <int F_IN, int F_OUT>
__global__ __launch_bounds__(256) void gemm_scale_kernel(const float* __restrict__ X,
                                                         const float* __restrict__ W,
                                                         const float* __restrict__ dinv,
                                                         float* __restrict__ TS, int n) {
    constexpr int ROWS = 8;
    constexpr int RSTRIDE = 256 / F_OUT;   // 4 (F_OUT=64) or 2 (F_OUT=128)
    constexpr int ACCN = ROWS / RSTRIDE;   // 2 or 4
    __shared__ float xs[ROWS][F_IN + 1];
    int row0 = blockIdx.x * ROWS;          // n % ROWS == 0 for N=100000
    for (int idx = threadIdx.x; idx < ROWS * F_IN; idx += 256) {
        int r = idx / F_IN, k = idx % F_IN;
        xs[r][k] = X[(size_t)(row0 + r) * F_IN + k];
    }
    __syncthreads();
    int col = threadIdx.x % F_OUT;
    int rs = threadIdx.x / F_OUT;
    float acc[ACCN];
#pragma unroll
    for (int a = 0; a < ACCN; ++a) acc[a] = 0.0f;
    for (int k = 0; k < F_IN; ++k) {
        float w = W[k * F_OUT + col];
#pragma unroll
        for (int a = 0; a < ACCN; ++a) acc[a] += xs[rs + a * RSTRIDE][k] * w;
    }
#pragma unroll
    for (int a = 0; a < ACCN; ++a) {
        int r = row0 + rs + a * RSTRIDE;
        TS[(size_t)r * F_OUT + col] = dinv[r] * acc[a];
    }
}

// ---------------- out = relu(dinv[i]*(sum_{e->i} ts[src] + ts[i]) + b) ----------------
template <int F>
__global__ __launch_bounds__(256) void pull_agg_kernel(const float* __restrict__ TS,
                                                       const int* __restrict__ rowptr,
                                                       const int* __restrict__ esrc,
                                                       const float* __restrict__ dinv,
                                                       const float* __restrict__ bias,
                                                       float* __restrict__ OUT, int n) {
    constexpr int TPN = F / 4;         // threads per node (float4 per thread)
    constexpr int NPB = 256 / TPN;     // nodes per block
    int li = threadIdx.x / TPN;
    int t = threadIdx.x % TPN;
    int node = blockIdx.x * NPB + li;
    if (node >= n) return;
    const float4* TS4 = (const float4*)TS;
    float4 acc = TS4[(size_t)node * TPN + t];   // self-loop term
    int jend = rowptr[node + 1];
    for (int j = rowptr[node]; j < jend; ++j) {
        int s = esrc[j];
        float4 v = TS4[(size_t)s * TPN + t];
        acc.x += v.x; acc.y += v.y; acc.z += v.z; acc.w += v.w;
    }
    float dv = dinv[node];
    float4 bb = ((const float4*)bias)[t];
    float4 o;
    o.x = fmaxf(dv * acc.x + bb.x, 0.0f);
    o.y = fmaxf(dv * acc.y + bb.y, 0.0f);
    o.z = fmaxf(dv * acc.z + bb.z, 0.0f);
    o.w = fmaxf(dv * acc.w + bb.w, 0.0f);
    ((float4*)OUT)[(size_t)node * TPN + t] = o;
}

// ---------------- mean-pool (batch sorted -> binary search range) + FC ----------------
__global__ __launch_bounds__(128) void pool_fc_kernel(const float* __restrict__ H,
                                                      const int* __restrict__ batch,
                                                      const float* __restrict__ Wfc,
                                                      const float* __restrict__ bfc,
                                                      float* __restrict__ OUT, int n) {
    int g = blockIdx.x;
    __shared__ int se[2];
    __shared__ float pooled[128];
    if (threadIdx.x < 2) {
        int target = g + threadIdx.x;  // lower_bound(batch, target)
        int lo = 0, hi = n;
        while (lo < hi) {
            int mid = (lo + hi) >> 1;
            if (batch[mid] < target) lo = mid + 1; else hi = mid;
        }
        se[threadIdx.x] = lo;
    }
    __syncthreads();
    int start = se[0], end = se[1];
    float s = 0.0f;
    for (int i = start; i < end; ++i) s += H[(size_t)i * 128 + threadIdx.x];
    float cntf = (float)max(end - start, 1);
    pooled[threadIdx.x] = s / cntf;
    __syncthreads();
    if (threadIdx.x < 10) {
        float o = bfc[threadIdx.x];
        for (int k = 0; k < 128; ++k) o += pooled[k] * Wfc[k * 10 + threadIdx.x];
        OUT[g * 10 + threadIdx.x] = o;
    }
}

extern "C" void kernel_launch(void* const* d_in, const int* in_sizes, int n_in,
                              void* d_out, int out_size, void* d_ws, size_t ws_size,
                              hipStream_t stream) {
    const int N = N_NODES, E = N_EDGES, G = N_GRAPHS;
    const float* x = (const float*)d_in[0];
    const int* ei = (const int*)d_in[1];
    const int* batch = (const int*)d_in[2];
    const float* W1 = (const float*)d_in[3];
    const float* b1 = (const float*)d_in[4];
    const float* W2 = (const float*)d_in[5];
    const float* b2 = (const float*)d_in[6];
    const float* W3 = (const float*)d_in[7];
    const float* b3 = (const float*)d_in[8];
    const float* Wfc = (const float*)d_in[9];
    const float* bfc = (const float*)d_in[10];
    const int* src = ei;
    const int* dst = ei + E;

    char* ws = (char*)d_ws;
    size_t off = 0;
    auto alloc = [&](size_t bytes) {
        void* p = ws + off;
        off = (off + bytes + 255) & ~(size_t)255;
        return p;
    };
    const int NB = (N + SCAN_CHUNK - 1) / SCAN_CHUNK;   // 98 (<=256 required)
    float* dinv = (float*)alloc((size_t)N * 4);
    int* cnt = (int*)alloc((size_t)N * 4);
    int* rowptr = (int*)alloc((size_t)(N + 1) * 4);
    int* bsums = (int*)alloc((size_t)NB * 4);
    int* bhist = (int*)alloc((size_t)NBUK * 4);
    int* boff = (int*)alloc((size_t)(NBUK + 1) * 4);
    int* bcursor = (int*)alloc((size_t)NBUK * 4);
    int* esrc = (int*)alloc((size_t)E * 4);
    float* T = (float*)alloc((size_t)N * 128 * 4);  // ts buffer
    float* A = (float*)alloc((size_t)N * 128 * 4);  // layer outputs (ping)
    float* B = (float*)alloc((size_t)N * 128 * 4);  // layer outputs (pong)
    int2* sorted = (int2*)B;  // alias: dead before layer 2 writes B

    // ---- graph preprocessing: bucket-sorted CSR build ----
    hipMemsetAsync(bhist, 0, (size_t)NBUK * 4, stream);
    bhist_kernel<<<128, 256, 0, stream>>>(dst, bhist, E);
    bscan_kernel<<<1, 256, 0, stream>>>(bhist, boff, bcursor);
    const int NTILES = (E + SCAT_TILE - 1) / SCAT_TILE;
    bucket_scatter_kernel<<<NTILES, 256, 0, stream>>>(src, dst, bcursor, sorted, E);
    bucket_count_kernel<<<NBUK, 256, 0, stream>>>(sorted, boff, cnt, dinv, N);
    scan_sums_kernel<<<NB, 256, 0, stream>>>(cnt, bsums, N);
    scan_write_kernel<<<NB, 256, 0, stream>>>(cnt, bsums, rowptr, N, NB);
    bucket_fill_kernel<<<NBUK, 256, 0, stream>>>(sorted, boff, rowptr, esrc, N);

    // ---- layer 1: 128 -> 64 ----
    gemm_scale_kernel<128, 64><<<N / 8, 256, 0, stream>>>(x, W1, dinv, T, N);
    pull_agg_kernel<64><<<N / 16, 256, 0, stream>>>(T, rowptr, esrc, dinv, b1, A, N);
    // ---- layer 2: 64 -> 128 ----
    gemm_scale_kernel<64, 128><<<N / 8, 256, 0, stream>>>(A, W2, dinv, T, N);
    pull_agg_kernel<128><<<N / 8, 256, 0, stream>>>(T, rowptr, esrc, dinv, b2, B, N);
    // ---- layer 3: 128 -> 128 ----
    gemm_scale_kernel<128, 128><<<N / 8, 256, 0, stream>>>(B, W3, dinv, T, N);
    pull_agg_kernel<128><<<N / 8, 256, 0, stream>>>(T, rowptr, esrc, dinv, b3, A, N);
    // ---- mean pool + FC ----
    pool_fc_kernel<<<G, 128, 0, stream>>>(A, batch, Wfc, bfc, (float*)d_out, N);
}

// Round 4
// 571.747 us; speedup vs baseline: 1.5823x; 1.1110x over previous
//
#include <hip/hip_runtime.h>
#include <hip/hip_bf16.h>

#define N_NODES 100000
#define N_EDGES 1600000
#define N_GRAPHS 1024
#define BUK_SHIFT 7         // 128 nodes per bucket
#define NBUK 782            // ceil(100000 / 128)
#define SCAT_EPT 16         // edges per thread in bucket_scatter
#define SCAT_TILE (256 * SCAT_EPT)

// packed edge: (src << 7) | (dst & 127); src < 2^17 so fits in 24 bits

// ---------------- bucket histogram (LDS-privatized) ----------------
__global__ __launch_bounds__(256) void bhist_kernel(const int* __restrict__ dst,
                                                    int* __restrict__ bhist, int E) {
    __shared__ int lh[NBUK];
    for (int i = threadIdx.x; i < NBUK; i += 256) lh[i] = 0;
    __syncthreads();
    int i = blockIdx.x * blockDim.x + threadIdx.x;
    int stride = gridDim.x * blockDim.x;
    for (; i < E; i += stride) atomicAdd(&lh[dst[i] >> BUK_SHIFT], 1);
    __syncthreads();
    for (int b = threadIdx.x; b < NBUK; b += 256)
        if (lh[b]) atomicAdd(&bhist[b], lh[b]);
}

// ---------------- exclusive scan of bucket hist (1 block) ----------------
__global__ __launch_bounds__(256) void bscan_kernel(const int* __restrict__ bhist,
                                                    int* __restrict__ boff,
                                                    int* __restrict__ bcursor) {
    __shared__ int lds[256];
    int tid = threadIdx.x;
    int i0 = tid * 4;
    int e[4];
#pragma unroll
    for (int k = 0; k < 4; ++k) e[k] = (i0 + k < NBUK) ? bhist[i0 + k] : 0;
    int ts = e[0] + e[1] + e[2] + e[3];
    lds[tid] = ts;
    __syncthreads();
    for (int off = 1; off < 256; off <<= 1) {
        int v = (tid >= off) ? lds[tid - off] : 0;
        __syncthreads();
        lds[tid] += v;
        __syncthreads();
    }
    int run = lds[tid] - ts;  // exclusive
#pragma unroll
    for (int k = 0; k < 4; ++k) {
        if (i0 + k < NBUK) { boff[i0 + k] = run; bcursor[i0 + k] = run; }
        run += e[k];
    }
    if (tid == 255) boff[NBUK] = lds[255];
}

// ---------------- scatter edges into bucket-sorted order (packed) ----------------
__global__ __launch_bounds__(256) void bucket_scatter_kernel(const int* __restrict__ src,
                                                             const int* __restrict__ dst,
                                                             int* __restrict__ bcursor,
                                                             int* __restrict__ sorted, int E) {
    __shared__ int lhist[NBUK];
    __shared__ int lbase[NBUK];
    for (int i = threadIdx.x; i < NBUK; i += 256) lhist[i] = 0;
    __syncthreads();
    int base_i = blockIdx.x * SCAT_TILE;
    int s[SCAT_EPT], d[SCAT_EPT], lp[SCAT_EPT];
#pragma unroll
    for (int k = 0; k < SCAT_EPT; ++k) {
        int i = base_i + k * 256 + threadIdx.x;
        if (i < E) {
            s[k] = src[i];
            d[k] = dst[i];
            lp[k] = atomicAdd(&lhist[d[k] >> BUK_SHIFT], 1);
        }
    }
    __syncthreads();
    for (int b = threadIdx.x; b < NBUK; b += 256) {
        int c = lhist[b];
        lbase[b] = c ? atomicAdd(&bcursor[b], c) : 0;
    }
    __syncthreads();
#pragma unroll
    for (int k = 0; k < SCAT_EPT; ++k) {
        int i = base_i + k * 256 + threadIdx.x;
        if (i < E) {
            int b = d[k] >> BUK_SHIFT;
            sorted[lbase[b] + lp[k]] = (s[k] << BUK_SHIFT) | (d[k] & 127);
        }
    }
}

// ---------------- fused: per-bucket count + dinv + rowptr (local scan) + CSR fill ----------------
__global__ __launch_bounds__(256) void bucket_build_kernel(const int* __restrict__ sorted,
                                                           const int* __restrict__ boff,
                                                           int* __restrict__ rowptr,
                                                           float* __restrict__ dinv,
                                                           int* __restrict__ esrc, int n) {
    __shared__ int ncnt[128];
    __shared__ int sc[128];
    __shared__ int lbase[128];
    __shared__ int lcur[128];
    int tid = threadIdx.x;
    int b = blockIdx.x;
    int start = boff[b], end = boff[b + 1];
    if (tid < 128) ncnt[tid] = 0;
    __syncthreads();
    for (int j = start + tid; j < end; j += 256)
        atomicAdd(&ncnt[sorted[j] & 127], 1);
    __syncthreads();
    if (tid < 128) sc[tid] = ncnt[tid];
    __syncthreads();
    for (int off = 1; off < 128; off <<= 1) {
        int v = 0;
        if (tid < 128 && tid >= off) v = sc[tid - off];
        __syncthreads();
        if (tid < 128) sc[tid] += v;
        __syncthreads();
    }
    if (tid < 128) {
        int excl = sc[tid] - ncnt[tid];
        lbase[tid] = start + excl;
        lcur[tid] = 0;
        int node = (b << BUK_SHIFT) + tid;
        if (node < n) {
            rowptr[node] = start + excl;
            dinv[node] = rsqrtf((float)ncnt[tid] + 1.0f);
        }
        if (node == n - 1) rowptr[n] = end;  // grand total (last valid node's bucket)
    }
    __syncthreads();
    for (int j = start + tid; j < end; j += 256) {
        int p = sorted[j];
        int ln = p & 127;
        int off = atomicAdd(&lcur[ln], 1);
        esrc[lbase[ln] + off] = p >> BUK_SHIFT;
    }
}

// ---------------- GEMM: EPI=0: TS = dinv[row]*(X@W) ; EPI=1: OUT = relu(X@W + b) ----------------
template <int F_IN, int F_OUT, int EPI>
__global__ __launch_bounds__(256) void gemm_kernel(const float* __restrict__ X,
                                                   const float* __restrict__ W,
                                                   const float* __restrict__ dinv,
                                                   const float* __restrict__ bias,
                                                   float* __restrict__ OUT, int n) {
    constexpr int ROWS = 8;
    constexpr int RSTRIDE = 256 / F_OUT;   // 4 (F_OUT=64) or 2 (F_OUT=128)
    constexpr int ACCN = ROWS / RSTRIDE;   // 2 or 4
    __shared__ float xs[ROWS][F_IN + 1];
    int row0 = blockIdx.x * ROWS;          // n % ROWS == 0 for N=100000
    for (int idx = threadIdx.x; idx < ROWS * F_IN; idx += 256) {
        int r = idx / F_IN, k = idx % F_IN;
        xs[r][k] = X[(size_t)(row0 + r) * F_IN + k];
    }
    __syncthreads();
    int col = threadIdx.x % F_OUT;
    int rs = threadIdx.x / F_OUT;
    float acc[ACCN];
#pragma unroll
    for (int a = 0; a < ACCN; ++a) acc[a] = 0.0f;
    for (int k = 0; k < F_IN; ++k) {
        float w = W[k * F_OUT + col];
#pragma unroll
        for (int a = 0; a < ACCN; ++a) acc[a] += xs[rs + a * RSTRIDE][k] * w;
    }
#pragma unroll
    for (int a = 0; a < ACCN; ++a) {
        int r = row0 + rs + a * RSTRIDE;
        if (EPI == 0) {
            OUT[(size_t)r * F_OUT + col] = dinv[r] * acc[a];
        } else {
            OUT[(size_t)r * F_OUT + col] = fmaxf(acc[a] + bias[col], 0.0f);
        }
    }
}

// ---------------- post-GEMM agg: out = relu(dinv[i]*(sum ts[src] + ts[i]) + b) ----------------
template <int F>
__global__ __launch_bounds__(256) void pull_agg_kernel(const float* __restrict__ TS,
                                                       const int* __restrict__ rowptr,
                                                       const int* __restrict__ esrc,
                                                       const float* __restrict__ dinv,
                                                       const float* __restrict__ bias,
                                                       float* __restrict__ OUT, int n) {
    constexpr int TPN = F / 4;         // threads per node (float4 per thread)
    constexpr int NPB = 256 / TPN;     // nodes per block
    int li = threadIdx.x / TPN;
    int t = threadIdx.x % TPN;
    int node = blockIdx.x * NPB + li;
    if (node >= n) return;
    const float4* TS4 = (const float4*)TS;
    float4 acc = TS4[(size_t)node * TPN + t];   // self-loop term
    int jend = rowptr[node + 1];
    for (int j = rowptr[node]; j < jend; ++j) {
        int s = esrc[j];
        float4 v = TS4[(size_t)s * TPN + t];
        acc.x += v.x; acc.y += v.y; acc.z += v.z; acc.w += v.w;
    }
    float dv = dinv[node];
    float4 bb = ((const float4*)bias)[t];
    float4 o;
    o.x = fmaxf(dv * acc.x + bb.x, 0.0f);
    o.y = fmaxf(dv * acc.y + bb.y, 0.0f);
    o.z = fmaxf(dv * acc.z + bb.z, 0.0f);
    o.w = fmaxf(dv * acc.w + bb.w, 0.0f);
    ((float4*)OUT)[(size_t)node * TPN + t] = o;
}

// ---------------- pre-GEMM agg: g = dinv[i]*(sum dinv[s]*h[s] + dinv[i]*h[i]) ----------------
template <int F>
__global__ __launch_bounds__(256) void pull_agg_pre_kernel(const float* __restrict__ H,
                                                           const int* __restrict__ rowptr,
                                                           const int* __restrict__ esrc,
                                                           const float* __restrict__ dinv,
                                                           float* __restrict__ OUT, int n) {
    constexpr int TPN = F / 4;
    constexpr int NPB = 256 / TPN;
    int li = threadIdx.x / TPN;
    int t = threadIdx.x % TPN;
    int node = blockIdx.x * NPB + li;
    if (node >= n) return;
    const float4* H4 = (const float4*)H;
    float dv = dinv[node];
    float4 self = H4[(size_t)node * TPN + t];
    float4 acc;
    acc.x = dv * self.x; acc.y = dv * self.y; acc.z = dv * self.z; acc.w = dv * self.w;
    int jend = rowptr[node + 1];
    for (int j = rowptr[node]; j < jend; ++j) {
        int s = esrc[j];
        float ds = dinv[s];
        float4 v = H4[(size_t)s * TPN + t];
        acc.x += ds * v.x; acc.y += ds * v.y; acc.z += ds * v.z; acc.w += ds * v.w;
    }
    float4 o;
    o.x = dv * acc.x; o.y = dv * acc.y; o.z = dv * acc.z; o.w = dv * acc.w;
    ((float4*)OUT)[(size_t)node * TPN + t] = o;
}

// ---------------- mean-pool (batch sorted -> binary search range) + FC ----------------
__global__ __launch_bounds__(128) void pool_fc_kernel(const float* __restrict__ H,
                                                      const int* __restrict__ batch,
                                                      const float* __restrict__ Wfc,
                                                      const float* __restrict__ bfc,
                                                      float* __restrict__ OUT, int n) {
    int g = blockIdx.x;
    __shared__ int se[2];
    __shared__ float pooled[128];
    if (threadIdx.x < 2) {
        int target = g + threadIdx.x;  // lower_bound(batch, target)
        int lo = 0, hi = n;
        while (lo < hi) {
            int mid = (lo + hi) >> 1;
            if (batch[mid] < target) lo = mid + 1; else hi = mid;
        }
        se[threadIdx.x] = lo;
    }
    __syncthreads();
    int start = se[0], end = se[1];
    float s = 0.0f;
    for (int i = start; i < end; ++i) s += H[(size_t)i * 128 + threadIdx.x];
    float cntf = (float)max(end - start, 1);
    pooled[threadIdx.x] = s / cntf;
    __syncthreads();
    if (threadIdx.x < 10) {
        float o = bfc[threadIdx.x];
        for (int k = 0; k < 128; ++k) o += pooled[k] * Wfc[k * 10 + threadIdx.x];
        OUT[g * 10 + threadIdx.x] = o;
    }
}

extern "C" void kernel_launch(void* const* d_in, const int* in_sizes, int n_in,
                              void* d_out, int out_size, void* d_ws, size_t ws_size,
                              hipStream_t stream) {
    const int N = N_NODES, E = N_EDGES, G = N_GRAPHS;
    const float* x = (const float*)d_in[0];
    const int* ei = (const int*)d_in[1];
    const int* batch = (const int*)d_in[2];
    const float* W1 = (const float*)d_in[3];
    const float* b1 = (const float*)d_in[4];
    const float* W2 = (const float*)d_in[5];
    const float* b2 = (const float*)d_in[6];
    const float* W3 = (const float*)d_in[7];
    const float* b3 = (const float*)d_in[8];
    const float* Wfc = (const float*)d_in[9];
    const float* bfc = (const float*)d_in[10];
    const int* src = ei;
    const int* dst = ei + E;

    char* ws = (char*)d_ws;
    size_t off = 0;
    auto alloc = [&](size_t bytes) {
        void* p = ws + off;
        off = (off + bytes + 255) & ~(size_t)255;
        return p;
    };
    float* dinv = (float*)alloc((size_t)N * 4);
    int* rowptr = (int*)alloc((size_t)(N + 1) * 4);
    int* bhist = (int*)alloc((size_t)NBUK * 4);
    int* boff = (int*)alloc((size_t)(NBUK + 1) * 4);
    int* bcursor = (int*)alloc((size_t)NBUK * 4);
    int* esrc = (int*)alloc((size_t)E * 4);
    float* T = (float*)alloc((size_t)N * 128 * 4);  // ts / g2 buffer
    float* A = (float*)alloc((size_t)N * 128 * 4);  // h1 / h3
    float* B = (float*)alloc((size_t)N * 128 * 4);  // h2 (aliases sorted during preproc)
    int* sorted = (int*)B;  // packed edges; dead before layer-2 gemm writes B

    // ---- graph preprocessing: bucket-sorted CSR build ----
    hipMemsetAsync(bhist, 0, (size_t)NBUK * 4, stream);
    bhist_kernel<<<128, 256, 0, stream>>>(dst, bhist, E);
    bscan_kernel<<<1, 256, 0, stream>>>(bhist, boff, bcursor);
    const int NTILES = (E + SCAT_TILE - 1) / SCAT_TILE;
    bucket_scatter_kernel<<<NTILES, 256, 0, stream>>>(src, dst, bcursor, sorted, E);
    bucket_build_kernel<<<NBUK, 256, 0, stream>>>(sorted, boff, rowptr, dinv, esrc, N);

    // ---- layer 1: 128 -> 64 (GEMM first, aggregate at 64) ----
    gemm_kernel<128, 64, 0><<<N / 8, 256, 0, stream>>>(x, W1, dinv, nullptr, T, N);
    pull_agg_kernel<64><<<N / 16, 256, 0, stream>>>(T, rowptr, esrc, dinv, b1, A, N);
    // ---- layer 2: 64 -> 128 (aggregate first at 64, then GEMM+bias+relu) ----
    pull_agg_pre_kernel<64><<<N / 16, 256, 0, stream>>>(A, rowptr, esrc, dinv, T, N);
    gemm_kernel<64, 128, 1><<<N / 8, 256, 0, stream>>>(T, W2, nullptr, b2, B, N);
    // ---- layer 3: 128 -> 128 (GEMM first) ----
    gemm_kernel<128, 128, 0><<<N / 8, 256, 0, stream>>>(B, W3, dinv, nullptr, T, N);
    pull_agg_kernel<128><<<N / 8, 256, 0, stream>>>(T, rowptr, esrc, dinv, b3, A, N);
    // ---- mean pool + FC ----
    pool_fc_kernel<<<G, 128, 0, stream>>>(A, batch, Wfc, bfc, (float*)d_out, N);
}

// Round 5
// 464.130 us; speedup vs baseline: 1.9492x; 1.2319x over previous
//
#include <hip/hip_runtime.h>
#include <hip/hip_bf16.h>

typedef unsigned int u32;

#define N_NODES 100000
#define N_EDGES 1600000
#define N_GRAPHS 1024
#define BUK_SHIFT 7         // 128 nodes per bucket
#define NBUK 782            // ceil(100000 / 128)
#define SCAT_EPT 16         // edges per thread in bucket_scatter
#define SCAT_TILE (256 * SCAT_EPT)

// ---- bf16 helpers (RNE) ----
__device__ __forceinline__ float bflo(u32 u) { return __uint_as_float(u << 16); }
__device__ __forceinline__ float bfhi(u32 u) { return __uint_as_float(u & 0xFFFF0000u); }
__device__ __forceinline__ u32 bf1(float a) {  // single f32 -> bf16 bits (RNE)
    u32 ua = __float_as_uint(a);
    ua += 0x7FFF + ((ua >> 16) & 1);
    return ua >> 16;
}
__device__ __forceinline__ u32 bfpack(float a, float b) {
    u32 ua = __float_as_uint(a);
    u32 ub = __float_as_uint(b);
    ua += 0x7FFF + ((ua >> 16) & 1);
    ub += 0x7FFF + ((ub >> 16) & 1);
    return (ua >> 16) | (ub & 0xFFFF0000u);
}
__device__ __forceinline__ void unpack8(uint4 v, float* f) {
    f[0] = bflo(v.x); f[1] = bfhi(v.x); f[2] = bflo(v.y); f[3] = bfhi(v.y);
    f[4] = bflo(v.z); f[5] = bfhi(v.z); f[6] = bflo(v.w); f[7] = bfhi(v.w);
}

// ---------------- bucket histogram (LDS-privatized) ----------------
__global__ __launch_bounds__(256) void bhist_kernel(const int* __restrict__ dst,
                                                    int* __restrict__ bhist, int E) {
    __shared__ int lh[NBUK];
    for (int i = threadIdx.x; i < NBUK; i += 256) lh[i] = 0;
    __syncthreads();
    int i = blockIdx.x * blockDim.x + threadIdx.x;
    int stride = gridDim.x * blockDim.x;
    for (; i < E; i += stride) atomicAdd(&lh[dst[i] >> BUK_SHIFT], 1);
    __syncthreads();
    for (int b = threadIdx.x; b < NBUK; b += 256)
        if (lh[b]) atomicAdd(&bhist[b], lh[b]);
}

// ---------------- exclusive scan of bucket hist (1 block) ----------------
__global__ __launch_bounds__(256) void bscan_kernel(const int* __restrict__ bhist,
                                                    int* __restrict__ boff,
                                                    int* __restrict__ bcursor) {
    __shared__ int lds[256];
    int tid = threadIdx.x;
    int i0 = tid * 4;
    int e[4];
#pragma unroll
    for (int k = 0; k < 4; ++k) e[k] = (i0 + k < NBUK) ? bhist[i0 + k] : 0;
    int ts = e[0] + e[1] + e[2] + e[3];
    lds[tid] = ts;
    __syncthreads();
    for (int off = 1; off < 256; off <<= 1) {
        int v = (tid >= off) ? lds[tid - off] : 0;
        __syncthreads();
        lds[tid] += v;
        __syncthreads();
    }
    int run = lds[tid] - ts;  // exclusive
#pragma unroll
    for (int k = 0; k < 4; ++k) {
        if (i0 + k < NBUK) { boff[i0 + k] = run; bcursor[i0 + k] = run; }
        run += e[k];
    }
    if (tid == 255) boff[NBUK] = lds[255];
}

// ---------------- scatter edges into bucket-sorted order (packed) ----------------
__global__ __launch_bounds__(256) void bucket_scatter_kernel(const int* __restrict__ src,
                                                             const int* __restrict__ dst,
                                                             int* __restrict__ bcursor,
                                                             int* __restrict__ sorted, int E) {
    __shared__ int lhist[NBUK];
    __shared__ int lbase[NBUK];
    for (int i = threadIdx.x; i < NBUK; i += 256) lhist[i] = 0;
    __syncthreads();
    int base_i = blockIdx.x * SCAT_TILE;
    int s[SCAT_EPT], d[SCAT_EPT], lp[SCAT_EPT];
#pragma unroll
    for (int k = 0; k < SCAT_EPT; ++k) {
        int i = base_i + k * 256 + threadIdx.x;
        if (i < E) {
            s[k] = src[i];
            d[k] = dst[i];
            lp[k] = atomicAdd(&lhist[d[k] >> BUK_SHIFT], 1);
        }
    }
    __syncthreads();
    for (int b = threadIdx.x; b < NBUK; b += 256) {
        int c = lhist[b];
        lbase[b] = c ? atomicAdd(&bcursor[b], c) : 0;
    }
    __syncthreads();
#pragma unroll
    for (int k = 0; k < SCAT_EPT; ++k) {
        int i = base_i + k * 256 + threadIdx.x;
        if (i < E) {
            int b = d[k] >> BUK_SHIFT;
            sorted[lbase[b] + lp[k]] = (s[k] << BUK_SHIFT) | (d[k] & 127);
        }
    }
}

// ---------------- fused: per-bucket count + dinv + rowptr (local scan) + CSR fill ----------------
__global__ __launch_bounds__(256) void bucket_build_kernel(const int* __restrict__ sorted,
                                                           const int* __restrict__ boff,
                                                           int* __restrict__ rowptr,
                                                           float* __restrict__ dinv,
                                                           int* __restrict__ esrc, int n) {
    __shared__ int ncnt[128];
    __shared__ int sc[128];
    __shared__ int lbase[128];
    __shared__ int lcur[128];
    int tid = threadIdx.x;
    int b = blockIdx.x;
    int start = boff[b], end = boff[b + 1];
    if (tid < 128) ncnt[tid] = 0;
    __syncthreads();
    for (int j = start + tid; j < end; j += 256)
        atomicAdd(&ncnt[sorted[j] & 127], 1);
    __syncthreads();
    if (tid < 128) sc[tid] = ncnt[tid];
    __syncthreads();
    for (int off = 1; off < 128; off <<= 1) {
        int v = 0;
        if (tid < 128 && tid >= off) v = sc[tid - off];
        __syncthreads();
        if (tid < 128) sc[tid] += v;
        __syncthreads();
    }
    if (tid < 128) {
        int excl = sc[tid] - ncnt[tid];
        lbase[tid] = start + excl;
        lcur[tid] = 0;
        int node = (b << BUK_SHIFT) + tid;
        if (node < n) {
            rowptr[node] = start + excl;
            dinv[node] = rsqrtf((float)ncnt[tid] + 1.0f);
        }
        if (node == n - 1) rowptr[n] = end;
    }
    __syncthreads();
    for (int j = start + tid; j < end; j += 256) {
        int p = sorted[j];
        int ln = p & 127;
        int off = atomicAdd(&lcur[ln], 1);
        esrc[lbase[ln] + off] = p >> BUK_SHIFT;
    }
}

// ---------------- GEMM: EPI=0: bf16 TS = dinv[row]*(X@W) ; EPI=1: f32 OUT = relu(X@W + b) ----------------
template <int F_IN, int F_OUT, int EPI>
__global__ __launch_bounds__(256) void gemm_kernel(const float* __restrict__ X,
                                                   const float* __restrict__ W,
                                                   const float* __restrict__ dinv,
                                                   const float* __restrict__ bias,
                                                   void* __restrict__ OUT, int n) {
    constexpr int ROWS = 8;
    constexpr int RSTRIDE = 256 / F_OUT;   // 4 (F_OUT=64) or 2 (F_OUT=128)
    constexpr int ACCN = ROWS / RSTRIDE;   // 2 or 4
    __shared__ float xs[ROWS][F_IN + 1];
    int row0 = blockIdx.x * ROWS;          // n % ROWS == 0 for N=100000
    for (int idx = threadIdx.x; idx < ROWS * F_IN; idx += 256) {
        int r = idx / F_IN, k = idx % F_IN;
        xs[r][k] = X[(size_t)(row0 + r) * F_IN + k];
    }
    __syncthreads();
    int col = threadIdx.x % F_OUT;
    int rs = threadIdx.x / F_OUT;
    float acc[ACCN];
#pragma unroll
    for (int a = 0; a < ACCN; ++a) acc[a] = 0.0f;
    for (int k = 0; k < F_IN; ++k) {
        float w = W[k * F_OUT + col];
#pragma unroll
        for (int a = 0; a < ACCN; ++a) acc[a] += xs[rs + a * RSTRIDE][k] * w;
    }
#pragma unroll
    for (int a = 0; a < ACCN; ++a) {
        int r = row0 + rs + a * RSTRIDE;
        if (EPI == 0) {
            ((unsigned short*)OUT)[(size_t)r * F_OUT + col] =
                (unsigned short)bf1(dinv[r] * acc[a]);
        } else {
            ((float*)OUT)[(size_t)r * F_OUT + col] = fmaxf(acc[a] + bias[col], 0.0f);
        }
    }
}

// ---- post-GEMM agg (bf16 gather): o = relu(dinv[i]*(sum ts[src] + ts[i]) + b) ----
// OUT_BF=1 -> bf16 output, OUT_BF=0 -> f32 output
template <int F, int OUT_BF>
__global__ __launch_bounds__(256) void pull_agg_b_kernel(const uint4* __restrict__ TS,
                                                         const int* __restrict__ rowptr,
                                                         const int* __restrict__ esrc,
                                                         const float* __restrict__ dinv,
                                                         const float* __restrict__ bias,
                                                         void* __restrict__ OUT, int n) {
    constexpr int TPN = F / 8;         // lanes per node, 16B (8 bf16) each
    constexpr int NPB = 256 / TPN;
    int li = threadIdx.x / TPN;
    int t = threadIdx.x % TPN;
    int node = blockIdx.x * NPB + li;
    if (node >= n) return;
    float acc[8], f[8];
    unpack8(TS[(size_t)node * TPN + t], acc);   // self-loop term
    int jend = rowptr[node + 1];
    for (int j = rowptr[node]; j < jend; ++j) {
        int s = esrc[j];
        unpack8(TS[(size_t)s * TPN + t], f);
#pragma unroll
        for (int k = 0; k < 8; ++k) acc[k] += f[k];
    }
    float dv = dinv[node];
    const float4* bias4 = (const float4*)bias;
    float4 b0 = bias4[t * 2], b1 = bias4[t * 2 + 1];
    float o[8];
    o[0] = fmaxf(dv * acc[0] + b0.x, 0.0f);
    o[1] = fmaxf(dv * acc[1] + b0.y, 0.0f);
    o[2] = fmaxf(dv * acc[2] + b0.z, 0.0f);
    o[3] = fmaxf(dv * acc[3] + b0.w, 0.0f);
    o[4] = fmaxf(dv * acc[4] + b1.x, 0.0f);
    o[5] = fmaxf(dv * acc[5] + b1.y, 0.0f);
    o[6] = fmaxf(dv * acc[6] + b1.z, 0.0f);
    o[7] = fmaxf(dv * acc[7] + b1.w, 0.0f);
    if (OUT_BF) {
        uint4 pv;
        pv.x = bfpack(o[0], o[1]); pv.y = bfpack(o[2], o[3]);
        pv.z = bfpack(o[4], o[5]); pv.w = bfpack(o[6], o[7]);
        ((uint4*)OUT)[(size_t)node * TPN + t] = pv;
    } else {
        float4* O4 = (float4*)OUT;
        O4[(size_t)node * (F / 4) + t * 2] = make_float4(o[0], o[1], o[2], o[3]);
        O4[(size_t)node * (F / 4) + t * 2 + 1] = make_float4(o[4], o[5], o[6], o[7]);
    }
}

// ---- pre-GEMM agg (bf16 gather): g = dinv[i]*(sum dinv[s]*h[s] + dinv[i]*h[i]), f32 out ----
template <int F>
__global__ __launch_bounds__(256) void pull_agg_pre_b_kernel(const uint4* __restrict__ H,
                                                             const int* __restrict__ rowptr,
                                                             const int* __restrict__ esrc,
                                                             const float* __restrict__ dinv,
                                                             float* __restrict__ OUT, int n) {
    constexpr int TPN = F / 8;
    constexpr int NPB = 256 / TPN;
    int li = threadIdx.x / TPN;
    int t = threadIdx.x % TPN;
    int node = blockIdx.x * NPB + li;
    if (node >= n) return;
    float acc[8], f[8];
    float dv = dinv[node];
    unpack8(H[(size_t)node * TPN + t], f);
#pragma unroll
    for (int k = 0; k < 8; ++k) acc[k] = dv * f[k];
    int jend = rowptr[node + 1];
    for (int j = rowptr[node]; j < jend; ++j) {
        int s = esrc[j];
        float ds = dinv[s];
        unpack8(H[(size_t)s * TPN + t], f);
#pragma unroll
        for (int k = 0; k < 8; ++k) acc[k] += ds * f[k];
    }
    float4* O4 = (float4*)OUT;
    O4[(size_t)node * (F / 4) + t * 2] =
        make_float4(dv * acc[0], dv * acc[1], dv * acc[2], dv * acc[3]);
    O4[(size_t)node * (F / 4) + t * 2 + 1] =
        make_float4(dv * acc[4], dv * acc[5], dv * acc[6], dv * acc[7]);
}

// ---------------- mean-pool (batch sorted -> binary search range) + FC ----------------
__global__ __launch_bounds__(128) void pool_fc_kernel(const float* __restrict__ H,
                                                      const int* __restrict__ batch,
                                                      const float* __restrict__ Wfc,
                                                      const float* __restrict__ bfc,
                                                      float* __restrict__ OUT, int n) {
    int g = blockIdx.x;
    __shared__ int se[2];
    __shared__ float pooled[128];
    if (threadIdx.x < 2) {
        int target = g + threadIdx.x;  // lower_bound(batch, target)
        int lo = 0, hi = n;
        while (lo < hi) {
            int mid = (lo + hi) >> 1;
            if (batch[mid] < target) lo = mid + 1; else hi = mid;
        }
        se[threadIdx.x] = lo;
    }
    __syncthreads();
    int start = se[0], end = se[1];
    float s = 0.0f;
    for (int i = start; i < end; ++i) s += H[(size_t)i * 128 + threadIdx.x];
    float cntf = (float)max(end - start, 1);
    pooled[threadIdx.x] = s / cntf;
    __syncthreads();
    if (threadIdx.x < 10) {
        float o = bfc[threadIdx.x];
        for (int k = 0; k < 128; ++k) o += pooled[k] * Wfc[k * 10 + threadIdx.x];
        OUT[g * 10 + threadIdx.x] = o;
    }
}

extern "C" void kernel_launch(void* const* d_in, const int* in_sizes, int n_in,
                              void* d_out, int out_size, void* d_ws, size_t ws_size,
                              hipStream_t stream) {
    const int N = N_NODES, E = N_EDGES, G = N_GRAPHS;
    const float* x = (const float*)d_in[0];
    const int* ei = (const int*)d_in[1];
    const int* batch = (const int*)d_in[2];
    const float* W1 = (const float*)d_in[3];
    const float* b1 = (const float*)d_in[4];
    const float* W2 = (const float*)d_in[5];
    const float* b2 = (const float*)d_in[6];
    const float* W3 = (const float*)d_in[7];
    const float* b3 = (const float*)d_in[8];
    const float* Wfc = (const float*)d_in[9];
    const float* bfc = (const float*)d_in[10];
    const int* src = ei;
    const int* dst = ei + E;

    char* ws = (char*)d_ws;
    size_t off = 0;
    auto alloc = [&](size_t bytes) {
        void* p = ws + off;
        off = (off + bytes + 255) & ~(size_t)255;
        return p;
    };
    float* dinv = (float*)alloc((size_t)N * 4);
    int* rowptr = (int*)alloc((size_t)(N + 1) * 4);
    int* bhist = (int*)alloc((size_t)NBUK * 4);
    int* boff = (int*)alloc((size_t)(NBUK + 1) * 4);
    int* bcursor = (int*)alloc((size_t)NBUK * 4);
    int* esrc = (int*)alloc((size_t)E * 4);
    unsigned short* TS1 = (unsigned short*)alloc((size_t)N * 64 * 2);   // bf16 [N][64]
    unsigned short* H1 = (unsigned short*)alloc((size_t)N * 64 * 2);    // bf16 [N][64]
    float* T = (float*)alloc((size_t)N * 128 * 4);  // g2 f32 [N][64] ; ts3 bf16 [N][128]
    float* A = (float*)alloc((size_t)N * 128 * 4);  // h3 f32
    float* B = (float*)alloc((size_t)N * 128 * 4);  // h2 f32 (aliases sorted during preproc)
    int* sorted = (int*)B;                          // packed edges; dead before gemm2 writes B
    unsigned short* TS3 = (unsigned short*)T;       // bf16 view; g2 dead after gemm2

    // ---- graph preprocessing: bucket-sorted CSR build ----
    hipMemsetAsync(bhist, 0, (size_t)NBUK * 4, stream);
    bhist_kernel<<<128, 256, 0, stream>>>(dst, bhist, E);
    bscan_kernel<<<1, 256, 0, stream>>>(bhist, boff, bcursor);
    const int NTILES = (E + SCAT_TILE - 1) / SCAT_TILE;
    bucket_scatter_kernel<<<NTILES, 256, 0, stream>>>(src, dst, bcursor, sorted, E);
    bucket_build_kernel<<<NBUK, 256, 0, stream>>>(sorted, boff, rowptr, dinv, esrc, N);

    // ---- layer 1: 128 -> 64 (GEMM -> bf16 ts1; aggregate at 64 -> bf16 h1) ----
    gemm_kernel<128, 64, 0><<<N / 8, 256, 0, stream>>>(x, W1, dinv, nullptr, TS1, N);
    pull_agg_b_kernel<64, 1><<<N / 32, 256, 0, stream>>>((const uint4*)TS1, rowptr, esrc,
                                                         dinv, b1, H1, N);
    // ---- layer 2: 64 -> 128 (aggregate-first at 64 -> f32 g2; GEMM+bias+relu -> f32 h2) ----
    pull_agg_pre_b_kernel<64><<<N / 32, 256, 0, stream>>>((const uint4*)H1, rowptr, esrc,
                                                          dinv, T, N);
    gemm_kernel<64, 128, 1><<<N / 8, 256, 0, stream>>>(T, W2, nullptr, b2, B, N);
    // ---- layer 3: 128 -> 128 (GEMM -> bf16 ts3; aggregate -> f32 h3) ----
    gemm_kernel<128, 128, 0><<<N / 8, 256, 0, stream>>>(B, W3, dinv, nullptr, TS3, N);
    pull_agg_b_kernel<128, 0><<<N / 16, 256, 0, stream>>>((const uint4*)TS3, rowptr, esrc,
                                                          dinv, b3, A, N);
    // ---- mean pool + FC ----
    pool_fc_kernel<<<G, 128, 0, stream>>>(A, batch, Wfc, bfc, (float*)d_out, N);
}

// Round 6
// 313.948 us; speedup vs baseline: 2.8816x; 1.4784x over previous
//
#include <hip/hip_runtime.h>
#include <hip/hip_bf16.h>

typedef unsigned int u32;
typedef unsigned short u16;
typedef __attribute__((ext_vector_type(8))) short short8;
typedef __attribute__((ext_vector_type(4))) float f32x4;

#define N_NODES 100000
#define N_EDGES 1600000
#define N_GRAPHS 1024
#define BUK_SHIFT 7         // 128 nodes per bucket
#define NBUK 782            // ceil(100000 / 128)
#define SCAT_EPT 16         // edges per thread in bucket_scatter
#define SCAT_TILE (256 * SCAT_EPT)

// ---- bf16 helpers (RNE) ----
__device__ __forceinline__ float bflo(u32 u) { return __uint_as_float(u << 16); }
__device__ __forceinline__ float bfhi(u32 u) { return __uint_as_float(u & 0xFFFF0000u); }
__device__ __forceinline__ u32 bf1(float a) {
    u32 ua = __float_as_uint(a);
    ua += 0x7FFF + ((ua >> 16) & 1);
    return ua >> 16;
}
__device__ __forceinline__ u32 bfpack(float a, float b) {
    u32 ua = __float_as_uint(a);
    u32 ub = __float_as_uint(b);
    ua += 0x7FFF + ((ua >> 16) & 1);
    ub += 0x7FFF + ((ub >> 16) & 1);
    return (ua >> 16) | (ub & 0xFFFF0000u);
}
__device__ __forceinline__ void unpack8(uint4 v, float* f) {
    f[0] = bflo(v.x); f[1] = bfhi(v.x); f[2] = bflo(v.y); f[3] = bfhi(v.y);
    f[4] = bflo(v.z); f[5] = bfhi(v.z); f[6] = bflo(v.w); f[7] = bfhi(v.w);
}

// ---------------- bucket histogram (LDS-privatized) ----------------
__global__ __launch_bounds__(256) void bhist_kernel(const int* __restrict__ dst,
                                                    int* __restrict__ bhist, int E) {
    __shared__ int lh[NBUK];
    for (int i = threadIdx.x; i < NBUK; i += 256) lh[i] = 0;
    __syncthreads();
    int i = blockIdx.x * blockDim.x + threadIdx.x;
    int stride = gridDim.x * blockDim.x;
    for (; i < E; i += stride) atomicAdd(&lh[dst[i] >> BUK_SHIFT], 1);
    __syncthreads();
    for (int b = threadIdx.x; b < NBUK; b += 256)
        if (lh[b]) atomicAdd(&bhist[b], lh[b]);
}

// ---------------- exclusive scan of bucket hist (1 block) ----------------
__global__ __launch_bounds__(256) void bscan_kernel(const int* __restrict__ bhist,
                                                    int* __restrict__ boff,
                                                    int* __restrict__ bcursor) {
    __shared__ int lds[256];
    int tid = threadIdx.x;
    int i0 = tid * 4;
    int e[4];
#pragma unroll
    for (int k = 0; k < 4; ++k) e[k] = (i0 + k < NBUK) ? bhist[i0 + k] : 0;
    int ts = e[0] + e[1] + e[2] + e[3];
    lds[tid] = ts;
    __syncthreads();
    for (int off = 1; off < 256; off <<= 1) {
        int v = (tid >= off) ? lds[tid - off] : 0;
        __syncthreads();
        lds[tid] += v;
        __syncthreads();
    }
    int run = lds[tid] - ts;  // exclusive
#pragma unroll
    for (int k = 0; k < 4; ++k) {
        if (i0 + k < NBUK) { boff[i0 + k] = run; bcursor[i0 + k] = run; }
        run += e[k];
    }
    if (tid == 255) boff[NBUK] = lds[255];
}

// ---------------- scatter edges into bucket-sorted order (packed) ----------------
__global__ __launch_bounds__(256) void bucket_scatter_kernel(const int* __restrict__ src,
                                                             const int* __restrict__ dst,
                                                             int* __restrict__ bcursor,
                                                             int* __restrict__ sorted, int E) {
    __shared__ int lhist[NBUK];
    __shared__ int lbase[NBUK];
    for (int i = threadIdx.x; i < NBUK; i += 256) lhist[i] = 0;
    __syncthreads();
    int base_i = blockIdx.x * SCAT_TILE;
    int s[SCAT_EPT], d[SCAT_EPT], lp[SCAT_EPT];
#pragma unroll
    for (int k = 0; k < SCAT_EPT; ++k) {
        int i = base_i + k * 256 + threadIdx.x;
        if (i < E) {
            s[k] = src[i];
            d[k] = dst[i];
            lp[k] = atomicAdd(&lhist[d[k] >> BUK_SHIFT], 1);
        }
    }
    __syncthreads();
    for (int b = threadIdx.x; b < NBUK; b += 256) {
        int c = lhist[b];
        lbase[b] = c ? atomicAdd(&bcursor[b], c) : 0;
    }
    __syncthreads();
#pragma unroll
    for (int k = 0; k < SCAT_EPT; ++k) {
        int i = base_i + k * 256 + threadIdx.x;
        if (i < E) {
            int b = d[k] >> BUK_SHIFT;
            sorted[lbase[b] + lp[k]] = (s[k] << BUK_SHIFT) | (d[k] & 127);
        }
    }
}

// ---------------- fused: per-bucket count + dinv + rowptr + CSR fill ----------------
__global__ __launch_bounds__(256) void bucket_build_kernel(const int* __restrict__ sorted,
                                                           const int* __restrict__ boff,
                                                           int* __restrict__ rowptr,
                                                           float* __restrict__ dinv,
                                                           int* __restrict__ esrc, int n) {
    __shared__ int ncnt[128];
    __shared__ int sc[128];
    __shared__ int lbase[128];
    __shared__ int lcur[128];
    int tid = threadIdx.x;
    int b = blockIdx.x;
    int start = boff[b], end = boff[b + 1];
    if (tid < 128) ncnt[tid] = 0;
    __syncthreads();
    for (int j = start + tid; j < end; j += 256)
        atomicAdd(&ncnt[sorted[j] & 127], 1);
    __syncthreads();
    if (tid < 128) sc[tid] = ncnt[tid];
    __syncthreads();
    for (int off = 1; off < 128; off <<= 1) {
        int v = 0;
        if (tid < 128 && tid >= off) v = sc[tid - off];
        __syncthreads();
        if (tid < 128) sc[tid] += v;
        __syncthreads();
    }
    if (tid < 128) {
        int excl = sc[tid] - ncnt[tid];
        lbase[tid] = start + excl;
        lcur[tid] = 0;
        int node = (b << BUK_SHIFT) + tid;
        if (node < n) {
            rowptr[node] = start + excl;
            dinv[node] = rsqrtf((float)ncnt[tid] + 1.0f);
        }
        if (node == n - 1) rowptr[n] = end;
    }
    __syncthreads();
    for (int j = start + tid; j < end; j += 256) {
        int p = sorted[j];
        int ln = p & 127;
        int off = atomicAdd(&lcur[ln], 1);
        esrc[lbase[ln] + off] = p >> BUK_SHIFT;
    }
}

// ---------------- W transpose + f32->bf16: Wt[n][k] = bf16(W[k][n]) ----------------
__global__ void convw_kernel(const float* __restrict__ W, u16* __restrict__ Wt,
                             int K, int Nout) {
    int i = blockIdx.x * 256 + threadIdx.x;
    if (i < K * Nout) {
        int n = i / K, k = i % K;
        Wt[i] = (u16)bf1(W[(size_t)k * Nout + n]);
    }
}

// ---------------- MFMA GEMM: C[M][NOUT] bf16 = A[M][K] @ Wt^T ----------------
// A_F32=1: A is f32, rows scaled by dinv on load (A := dinv[r]*A[r])
// EPI=0:   C = A@W (pack bf16)
// EPI=1:   C = bf16( dinv[r] * relu(A@W + bias) )
template <int K, int NOUT, int EPI, int A_F32>
__global__ __launch_bounds__(256) void mfma_gemm_kernel(const void* __restrict__ Aptr,
                                                        const u16* __restrict__ Wt,
                                                        const float* __restrict__ bias,
                                                        const float* __restrict__ dinv,
                                                        u16* __restrict__ C, int M) {
    constexpr int KP = K + 8;         // padded LDS row (bf16 elems): stride 272/144B
    constexpr int NK = K / 32;        // mfma k-steps
    constexpr int NCT = NOUT / 16;    // col tiles
    __shared__ u16 wlds[NOUT * KP];
    int tid = threadIdx.x;
    constexpr int TOT = NOUT * K / 8; // uint4 elements of Wt
    const uint4* wt4 = (const uint4*)Wt;
    for (int i = tid; i < TOT; i += 256) {
        int r = i / (K / 8), kc = i % (K / 8);
        *(uint4*)&wlds[r * KP + kc * 8] = wt4[i];
    }
    __syncthreads();

    int lane = tid & 63;
    int w = tid >> 6;
    int row0 = blockIdx.x * 256 + w * 64;

    // preload A fragments: afr[sub][ks], rows row0+sub*16+(lane&15)
    short8 afr[4][NK];
#pragma unroll
    for (int sub = 0; sub < 4; ++sub) {
        int arow = row0 + sub * 16 + (lane & 15);
        arow = min(arow, M - 1);
        if (A_F32) {
            const float* Af = (const float*)Aptr;
            float dv = dinv[arow];
#pragma unroll
            for (int ks = 0; ks < NK; ++ks) {
                int k0 = ks * 32 + (lane >> 4) * 8;
                const float4* p = (const float4*)(Af + (size_t)arow * K + k0);
                float4 uu = p[0], vv = p[1];
                uint4 q;
                q.x = bfpack(dv * uu.x, dv * uu.y);
                q.y = bfpack(dv * uu.z, dv * uu.w);
                q.z = bfpack(dv * vv.x, dv * vv.y);
                q.w = bfpack(dv * vv.z, dv * vv.w);
                afr[sub][ks] = *(short8*)&q;
            }
        } else {
            const u16* Ab = (const u16*)Aptr;
#pragma unroll
            for (int ks = 0; ks < NK; ++ks) {
                int k0 = ks * 32 + (lane >> 4) * 8;
                afr[sub][ks] = *(const short8*)(Ab + (size_t)arow * K + k0);
            }
        }
    }

    for (int ct = 0; ct < NCT; ++ct) {
        int bcol = ct * 16 + (lane & 15);
        short8 bfr[NK];
#pragma unroll
        for (int ks = 0; ks < NK; ++ks) {
            int k0 = ks * 32 + (lane >> 4) * 8;
            bfr[ks] = *(const short8*)&wlds[bcol * KP + k0];
        }
        float bc = 0.0f;
        if (EPI == 1) bc = bias[bcol];
#pragma unroll
        for (int sub = 0; sub < 4; ++sub) {
            f32x4 acc = {0.0f, 0.0f, 0.0f, 0.0f};
#pragma unroll
            for (int ks = 0; ks < NK; ++ks)
                acc = __builtin_amdgcn_mfma_f32_16x16x32_bf16(afr[sub][ks], bfr[ks], acc,
                                                              0, 0, 0);
            int rbase = row0 + sub * 16 + (lane >> 4) * 4;  // rbase % 4 == 0, M % 4 == 0
            if (rbase < M) {
                if (EPI == 0) {
#pragma unroll
                    for (int j = 0; j < 4; ++j)
                        C[(size_t)(rbase + j) * NOUT + bcol] = (u16)bf1(acc[j]);
                } else {
                    float4 dv4 = *(const float4*)(dinv + rbase);
                    float dvv[4] = {dv4.x, dv4.y, dv4.z, dv4.w};
#pragma unroll
                    for (int j = 0; j < 4; ++j) {
                        float o = dvv[j] * fmaxf(acc[j] + bc, 0.0f);
                        C[(size_t)(rbase + j) * NOUT + bcol] = (u16)bf1(o);
                    }
                }
            }
        }
    }
}

// ---- post-GEMM agg (bf16 gather): o = relu(dinv[i]*(sum ts[src] + ts[i]) + b) ----
template <int F, int OUT_BF>
__global__ __launch_bounds__(256) void pull_agg_b_kernel(const uint4* __restrict__ TS,
                                                         const int* __restrict__ rowptr,
                                                         const int* __restrict__ esrc,
                                                         const float* __restrict__ dinv,
                                                         const float* __restrict__ bias,
                                                         void* __restrict__ OUT, int n) {
    constexpr int TPN = F / 8;
    constexpr int NPB = 256 / TPN;
    int li = threadIdx.x / TPN;
    int t = threadIdx.x % TPN;
    int node = blockIdx.x * NPB + li;
    if (node >= n) return;
    float acc[8], f[8];
    unpack8(TS[(size_t)node * TPN + t], acc);
    int jend = rowptr[node + 1];
    for (int j = rowptr[node]; j < jend; ++j) {
        int s = esrc[j];
        unpack8(TS[(size_t)s * TPN + t], f);
#pragma unroll
        for (int k = 0; k < 8; ++k) acc[k] += f[k];
    }
    float dv = dinv[node];
    const float4* bias4 = (const float4*)bias;
    float4 b0 = bias4[t * 2], b1 = bias4[t * 2 + 1];
    float o[8];
    o[0] = fmaxf(dv * acc[0] + b0.x, 0.0f);
    o[1] = fmaxf(dv * acc[1] + b0.y, 0.0f);
    o[2] = fmaxf(dv * acc[2] + b0.z, 0.0f);
    o[3] = fmaxf(dv * acc[3] + b0.w, 0.0f);
    o[4] = fmaxf(dv * acc[4] + b1.x, 0.0f);
    o[5] = fmaxf(dv * acc[5] + b1.y, 0.0f);
    o[6] = fmaxf(dv * acc[6] + b1.z, 0.0f);
    o[7] = fmaxf(dv * acc[7] + b1.w, 0.0f);
    if (OUT_BF) {
        uint4 pv;
        pv.x = bfpack(o[0], o[1]); pv.y = bfpack(o[2], o[3]);
        pv.z = bfpack(o[4], o[5]); pv.w = bfpack(o[6], o[7]);
        ((uint4*)OUT)[(size_t)node * TPN + t] = pv;
    } else {
        float4* O4 = (float4*)OUT;
        O4[(size_t)node * (F / 4) + t * 2] = make_float4(o[0], o[1], o[2], o[3]);
        O4[(size_t)node * (F / 4) + t * 2 + 1] = make_float4(o[4], o[5], o[6], o[7]);
    }
}

// ---- pre-GEMM agg (bf16 gather): g = dinv[i]*(sum dinv[s]*h[s] + dinv[i]*h[i]) ----
template <int F, int OUT_BF>
__global__ __launch_bounds__(256) void pull_agg_pre_b_kernel(const uint4* __restrict__ H,
                                                             const int* __restrict__ rowptr,
                                                             const int* __restrict__ esrc,
                                                             const float* __restrict__ dinv,
                                                             void* __restrict__ OUT, int n) {
    constexpr int TPN = F / 8;
    constexpr int NPB = 256 / TPN;
    int li = threadIdx.x / TPN;
    int t = threadIdx.x % TPN;
    int node = blockIdx.x * NPB + li;
    if (node >= n) return;
    float acc[8], f[8];
    float dv = dinv[node];
    unpack8(H[(size_t)node * TPN + t], f);
#pragma unroll
    for (int k = 0; k < 8; ++k) acc[k] = dv * f[k];
    int jend = rowptr[node + 1];
    for (int j = rowptr[node]; j < jend; ++j) {
        int s = esrc[j];
        float ds = dinv[s];
        unpack8(H[(size_t)s * TPN + t], f);
#pragma unroll
        for (int k = 0; k < 8; ++k) acc[k] += ds * f[k];
    }
    if (OUT_BF) {
        uint4 pv;
        pv.x = bfpack(dv * acc[0], dv * acc[1]);
        pv.y = bfpack(dv * acc[2], dv * acc[3]);
        pv.z = bfpack(dv * acc[4], dv * acc[5]);
        pv.w = bfpack(dv * acc[6], dv * acc[7]);
        ((uint4*)OUT)[(size_t)node * TPN + t] = pv;
    } else {
        float4* O4 = (float4*)OUT;
        O4[(size_t)node * (F / 4) + t * 2] =
            make_float4(dv * acc[0], dv * acc[1], dv * acc[2], dv * acc[3]);
        O4[(size_t)node * (F / 4) + t * 2 + 1] =
            make_float4(dv * acc[4], dv * acc[5], dv * acc[6], dv * acc[7]);
    }
}

// ---------------- mean-pool (batch sorted -> binary search range) + FC ----------------
__global__ __launch_bounds__(128) void pool_fc_kernel(const float* __restrict__ H,
                                                      const int* __restrict__ batch,
                                                      const float* __restrict__ Wfc,
                                                      const float* __restrict__ bfc,
                                                      float* __restrict__ OUT, int n) {
    int g = blockIdx.x;
    __shared__ int se[2];
    __shared__ float pooled[128];
    if (threadIdx.x < 2) {
        int target = g + threadIdx.x;
        int lo = 0, hi = n;
        while (lo < hi) {
            int mid = (lo + hi) >> 1;
            if (batch[mid] < target) lo = mid + 1; else hi = mid;
        }
        se[threadIdx.x] = lo;
    }
    __syncthreads();
    int start = se[0], end = se[1];
    float s = 0.0f;
    for (int i = start; i < end; ++i) s += H[(size_t)i * 128 + threadIdx.x];
    float cntf = (float)max(end - start, 1);
    pooled[threadIdx.x] = s / cntf;
    __syncthreads();
    if (threadIdx.x < 10) {
        float o = bfc[threadIdx.x];
        for (int k = 0; k < 128; ++k) o += pooled[k] * Wfc[k * 10 + threadIdx.x];
        OUT[g * 10 + threadIdx.x] = o;
    }
}

extern "C" void kernel_launch(void* const* d_in, const int* in_sizes, int n_in,
                              void* d_out, int out_size, void* d_ws, size_t ws_size,
                              hipStream_t stream) {
    const int N = N_NODES, E = N_EDGES, G = N_GRAPHS;
    const float* x = (const float*)d_in[0];
    const int* ei = (const int*)d_in[1];
    const int* batch = (const int*)d_in[2];
    const float* W1 = (const float*)d_in[3];
    const float* b1 = (const float*)d_in[4];
    const float* W2 = (const float*)d_in[5];
    const float* b2 = (const float*)d_in[6];
    const float* W3 = (const float*)d_in[7];
    const float* b3 = (const float*)d_in[8];
    const float* Wfc = (const float*)d_in[9];
    const float* bfc = (const float*)d_in[10];
    const int* src = ei;
    const int* dst = ei + E;

    char* ws = (char*)d_ws;
    size_t off = 0;
    auto alloc = [&](size_t bytes) {
        void* p = ws + off;
        off = (off + bytes + 255) & ~(size_t)255;
        return p;
    };
    float* dinv = (float*)alloc((size_t)N * 4);
    int* rowptr = (int*)alloc((size_t)(N + 1) * 4);
    int* bhist = (int*)alloc((size_t)NBUK * 4);
    int* boff = (int*)alloc((size_t)(NBUK + 1) * 4);
    int* bcursor = (int*)alloc((size_t)NBUK * 4);
    int* esrc = (int*)alloc((size_t)E * 4);
    u16* W1t = (u16*)alloc((size_t)64 * 128 * 2);    // [64][128]
    u16* W2t = (u16*)alloc((size_t)128 * 64 * 2);    // [128][64]
    u16* W3t = (u16*)alloc((size_t)128 * 128 * 2);   // [128][128]
    u16* TS1 = (u16*)alloc((size_t)N * 64 * 2);      // bf16 [N][64]
    u16* H1 = (u16*)alloc((size_t)N * 64 * 2);       // bf16 [N][64]
    u16* G2 = (u16*)alloc((size_t)N * 64 * 2);       // bf16 [N][64]
    u16* H2S = (u16*)alloc((size_t)N * 128 * 2);     // bf16 [N][128], pre-scaled by dinv
    u16* TS3 = (u16*)alloc((size_t)N * 128 * 2);     // bf16 [N][128]
    float* H3 = (float*)alloc((size_t)N * 128 * 4);  // f32 [N][128]
    int* sorted = (int*)TS3;  // packed edges during preproc; TS3 written later

    // ---- graph preprocessing: bucket-sorted CSR build ----
    hipMemsetAsync(bhist, 0, (size_t)NBUK * 4, stream);
    bhist_kernel<<<128, 256, 0, stream>>>(dst, bhist, E);
    bscan_kernel<<<1, 256, 0, stream>>>(bhist, boff, bcursor);
    const int NTILES = (E + SCAT_TILE - 1) / SCAT_TILE;
    bucket_scatter_kernel<<<NTILES, 256, 0, stream>>>(src, dst, bcursor, sorted, E);
    bucket_build_kernel<<<NBUK, 256, 0, stream>>>(sorted, boff, rowptr, dinv, esrc, N);

    // ---- weight conversion (transposed bf16) ----
    convw_kernel<<<32, 256, 0, stream>>>(W1, W1t, 128, 64);
    convw_kernel<<<32, 256, 0, stream>>>(W2, W2t, 64, 128);
    convw_kernel<<<64, 256, 0, stream>>>(W3, W3t, 128, 128);

    const int GEMM_GRID = (N + 255) / 256;
    // ---- layer 1: 128 -> 64 : ts1 = (dinv*x) @ W1 ----
    mfma_gemm_kernel<128, 64, 0, 1><<<GEMM_GRID, 256, 0, stream>>>(x, W1t, nullptr, dinv,
                                                                   TS1, N);
    pull_agg_b_kernel<64, 1><<<N / 32, 256, 0, stream>>>((const uint4*)TS1, rowptr, esrc,
                                                         dinv, b1, H1, N);
    // ---- layer 2: 64 -> 128 : g2 = Ahat-gather(h1); h2s = dinv*relu(g2@W2+b2) ----
    pull_agg_pre_b_kernel<64, 1><<<N / 32, 256, 0, stream>>>((const uint4*)H1, rowptr, esrc,
                                                             dinv, G2, N);
    mfma_gemm_kernel<64, 128, 1, 0><<<GEMM_GRID, 256, 0, stream>>>(G2, W2t, b2, dinv,
                                                                   H2S, N);
    // ---- layer 3: 128 -> 128 : ts3 = h2s @ W3 ; h3 = relu(dinv*(gather)+b3) ----
    mfma_gemm_kernel<128, 128, 0, 0><<<GEMM_GRID, 256, 0, stream>>>(H2S, W3t, nullptr, dinv,
                                                                    TS3, N);
    pull_agg_b_kernel<128, 0><<<N / 16, 256, 0, stream>>>((const uint4*)TS3, rowptr, esrc,
                                                          dinv, b3, H3, N);
    // ---- mean pool + FC ----
    pool_fc_kernel<<<G, 128, 0, stream>>>(H3, batch, Wfc, bfc, (float*)d_out, N);
}